// Round 7
// baseline (116.992 us; speedup 1.0000x reference)
//
#include <hip/hip_runtime.h>
#include <stdint.h>

// Problem constants (fixed by setup_inputs: B=4, N_obj=8, N_v=2048)
#define NPTS 2048
#define KNN  16
#define AK   64
#define TPB  256
#define FPT  (NPTS / TPB)   // 8 points per thread
#define KPL  (NPTS / 64)    // 32 points per lane (one wave per anchor)

typedef unsigned long long u64;
typedef unsigned int u32;
typedef unsigned short u16;
#define UMAX 0xFFFFFFFFFFFFFFFFull

// Exact float32 helpers (no FMA contraction -> match reference bitwise)
__device__ __forceinline__ float sq3(float x, float y, float z) {
    return __fadd_rn(__fadd_rn(__fmul_rn(x, x), __fmul_rn(y, y)), __fmul_rn(z, z));
}

// ---------------------------------------------------------------------------
// 64-lane butterfly reductions on u64 keys, ALL-VALU.
// Stages 1,2,4,8: DPP permutations (xor1/xor2/xor4/xor8 once groups uniform).
// Stages 16,32: gfx950 v_permlane16_swap / v_permlane32_swap with self;
// reducing with BOTH results realizes the xor exchange (self-compares are
// no-ops). Harness-verified (absmax 0.0) in rounds 1-6.
// ---------------------------------------------------------------------------
template <int CTRL>
__device__ __forceinline__ u64 dpp64(u64 k) {
    const int lo = __builtin_amdgcn_update_dpp((int)(u32)k, (int)(u32)k,
                                               CTRL, 0xF, 0xF, false);
    const int hi = __builtin_amdgcn_update_dpp((int)(u32)(k >> 32),
                                               (int)(u32)(k >> 32),
                                               CTRL, 0xF, 0xF, false);
    return ((u64)(u32)hi << 32) | (u32)lo;
}

__device__ __forceinline__ void swap16_pair(u64 k, u64& a, u64& b) {
#if __has_builtin(__builtin_amdgcn_permlane16_swap)
    const u32 lo = (u32)k, hi = (u32)(k >> 32);
    const auto rl = __builtin_amdgcn_permlane16_swap(lo, lo, false, false);
    const auto rh = __builtin_amdgcn_permlane16_swap(hi, hi, false, false);
    a = ((u64)(u32)rh[0] << 32) | (u32)rl[0];
    b = ((u64)(u32)rh[1] << 32) | (u32)rl[1];
#else
    a = (u64)__shfl_xor((long long)k, 16, 64);
    b = a;
#endif
}

__device__ __forceinline__ void swap32_pair(u64 k, u64& a, u64& b) {
#if __has_builtin(__builtin_amdgcn_permlane32_swap)
    const u32 lo = (u32)k, hi = (u32)(k >> 32);
    const auto rl = __builtin_amdgcn_permlane32_swap(lo, lo, false, false);
    const auto rh = __builtin_amdgcn_permlane32_swap(hi, hi, false, false);
    a = ((u64)(u32)rh[0] << 32) | (u32)rl[0];
    b = ((u64)(u32)rh[1] << 32) | (u32)rl[1];
#else
    a = (u64)__shfl_xor((long long)k, 32, 64);
    b = a;
#endif
}

__device__ __forceinline__ u64 wave_max64(u64 k) {
    u64 o, a, b;
    o = dpp64<0xB1>(k);  if (o > k) k = o;
    o = dpp64<0x4E>(k);  if (o > k) k = o;
    o = dpp64<0x141>(k); if (o > k) k = o;
    o = dpp64<0x140>(k); if (o > k) k = o;
    swap16_pair(k, a, b); if (a > k) k = a; if (b > k) k = b;
    swap32_pair(k, a, b); if (a > k) k = a; if (b > k) k = b;
    return k;
}

__device__ __forceinline__ u64 wave_min64(u64 k) {
    u64 o, a, b;
    o = dpp64<0xB1>(k);  if (o < k) k = o;
    o = dpp64<0x4E>(k);  if (o < k) k = o;
    o = dpp64<0x141>(k); if (o < k) k = o;
    o = dpp64<0x140>(k); if (o < k) k = o;
    swap16_pair(k, a, b); if (a < k) k = a; if (b < k) k = b;
    swap32_pair(k, a, b); if (a < k) k = a; if (b < k) k = b;
    return k;
}

// ---------------------------------------------------------------------------
// FUSED kernel, redundant-recompute edition. 512 blocks (16 per object),
// ZERO cross-block communication (no workspace, no memset, no atomics).
// Block (obj, q) computes the fps anchor chain itself, TRUNCATED to step
// 4q+3 (fps is deterministic: every block's prefix is bitwise identical to
// the full run), then performs the KNN/gather for anchors 4q..4q+3 (one
// wave per anchor). Block q=0 runs 3 fps steps; q=15 runs all 63.
// Kernel time = slowest block = one full fps chain + one knn body; the
// 8.6x extra fps step-work is free parallel slack (machine was 1.2%
// occupied). All 512 blocks co-resident (66KB LDS/CU of 160, 8 waves/CU
// of 32) but correctness does NOT depend on residency or dispatch order.
// vs R6 (49.3us kernel + memset dispatch): removes the publish stores'
// vmcnt-ack on the fps critical path, the consumer poll, and one of the
// two dispatches (~10us harness overhead each).
// fps body = R2's best-measured structure (41.4us), verified; knn body =
// verified bytes; both unchanged except delivery of `a` from registers.
// ---------------------------------------------------------------------------
__global__ __launch_bounds__(TPB) void fused_kernel(
    const float* __restrict__ pos, const float* __restrict__ vel,
    const float* __restrict__ phys, const float* __restrict__ refp,
    float* __restrict__ out, int n_obj) {
    const int b = blockIdx.x;
    const int obj = b >> 4;
    const int q = b & 15;               // anchor quad this block produces
    const int t = threadIdx.x;
    const int wid = t >> 6, lane = t & 63;

    __shared__ float4 sP[NPTS];   // (x,y,z,sq): fps reads xyz, knn reads all
    __shared__ u64 skey[8];       // fps: double-buffered per-wave winner keys
    __shared__ float4 scrd[8];    // fps: double-buffered per-wave winner coords

    const float* pts = pos + (size_t)obj * NPTS * 3;
    float px[FPT], py[FPT], pz[FPT], mind[FPT];
    #pragma unroll
    for (int i = 0; i < FPT; i++) {
        const int j = t + i * TPB;
        const float x = pts[j * 3 + 0];
        const float y = pts[j * 3 + 1];
        const float z = pts[j * 3 + 2];
        px[i] = x; py[i] = y; pz[i] = z;
        sP[j] = make_float4(x, y, z, sq3(x, y, z));
    }
    __syncthreads();

    // ======================= FPS phase (truncated) ==========================
    u32 a0 = 0, a1 = 0, a2 = 0, a3 = 0;   // this block's 4 anchors

    u64 key;
    {
        const float4 c0 = sP[0];   // broadcast read; xyz bits == pts[0..2]
        float bv = -1.0f; u32 bj = 0;
        #pragma unroll
        for (int i = 0; i < FPT; i++) {
            const float d2 = sq3(__fsub_rn(px[i], c0.x), __fsub_rn(py[i], c0.y),
                                 __fsub_rn(pz[i], c0.z));
            mind[i] = d2;
            if (d2 > bv) { bv = d2; bj = (u32)(t + i * TPB); }  // smallest j on ties
        }
        // mind >= 0 -> float bits order-monotonic; ~j -> smaller j wins ties
        key = ((u64)__float_as_uint(bv) << 32) | (u32)(~bj);
    }

    const int smax = q * 4 + 3;   // last fps step this block needs
    #pragma unroll 1
    for (int s = 1; s <= smax; s++) {
        const u64 wk = wave_max64(key);     // all lanes hold wave-winner
        const int side = (s & 1) * 4;
        if (lane == 0) {
            const int widx = (int)(~(u32)wk);
            skey[side + wid] = wk;
            scrd[side + wid] = sP[widx];    // 1x broadcast ds_read_b128
        }
        __syncthreads();   // only barrier per step; no vmem outstanding
        u64 ka = skey[side + 0];
        float4 ca = scrd[side + 0];
        { const u64 k1 = skey[side + 1]; const float4 qq = scrd[side + 1];
          if (k1 > ka) { ka = k1; ca = qq; } }
        { const u64 k2 = skey[side + 2]; const float4 qq = scrd[side + 2];
          if (k2 > ka) { ka = k2; ca = qq; } }
        { const u64 k3 = skey[side + 3]; const float4 qq = scrd[side + 3];
          if (k3 > ka) { ka = k3; ca = qq; } }

        // record anchors in this block's quad (computed by ALL threads)
        const u32 aid = ~(u32)ka;
        const int r = s - q * 4;
        if (r == 0) a0 = aid;
        else if (r == 1) a1 = aid;
        else if (r == 2) a2 = aid;
        else if (r == 3) a3 = aid;
        if (s == smax) break;   // no min-update needed after the last anchor

        // fused min-update + argmax scan (exact (p-b)^2 like lax.scan)
        float bv = -1.0f; u32 bj = 0;
        #pragma unroll
        for (int i = 0; i < FPT; i++) {
            const float d2 = sq3(__fsub_rn(px[i], ca.x), __fsub_rn(py[i], ca.y),
                                 __fsub_rn(pz[i], ca.z));
            const float nm = fminf(mind[i], d2);
            mind[i] = nm;
            if (nm > bv) { bv = nm; bj = (u32)(t + i * TPB); }
        }
        key = ((u64)__float_as_uint(bv) << 32) | (u32)(~bj);
    }

    // ======================= KNN phase (verified body) ======================
    u32 av = a0;
    if (wid == 1) av = a1;
    else if (wid == 2) av = a2;
    else if (wid == 3) av = a3;
    const int a = (int)av;                  // this wave's anchor
    const int g = obj * AK + q * 4 + wid;   // global anchor id

    const float4 ca = sP[a];
    const float ax = ca.x, ay = ca.y, az = ca.z;
    const float sqa = ca.w;     // identical bits to reference's sq[a]

    // d2 row exactly as reference: (sq_a + sq_j) - 2*dot, sign-flip sortable.
    u64 k[KPL];
    #pragma unroll
    for (int i = 0; i < KPL; i++) {
        const int j = lane + i * 64;
        const float4 p = sP[j];
        const float dot = __fadd_rn(
            __fadd_rn(__fmul_rn(ax, p.x), __fmul_rn(ay, p.y)), __fmul_rn(az, p.z));
        const float d2 = __fsub_rn(__fadd_rn(sqa, p.w), __fmul_rn(2.0f, dot));
        u32 bb = __float_as_uint(d2);
        bb ^= (bb & 0x80000000u) ? 0xFFFFFFFFu : 0x80000000u;
        k[i] = (j == a) ? UMAX : (((u64)bb << 32) | (u32)j);
    }

    // per-lane 4 smallest, ascending: c0 < c1 < c2 < c3 (keys unique)
    u64 c0 = UMAX, c1 = UMAX, c2 = UMAX, c3 = UMAX;
    #pragma unroll
    for (int i = 0; i < KPL; i++) c0 = (k[i] < c0) ? k[i] : c0;
    #pragma unroll
    for (int i = 0; i < KPL; i++) {
        const u64 v = (k[i] > c0) ? k[i] : UMAX; c1 = (v < c1) ? v : c1;
    }
    #pragma unroll
    for (int i = 0; i < KPL; i++) {
        const u64 v = (k[i] > c1) ? k[i] : UMAX; c2 = (v < c2) ? v : c2;
    }
    #pragma unroll
    for (int i = 0; i < KPL; i++) {
        const u64 v = (k[i] > c2) ? k[i] : UMAX; c3 = (v < c3) ? v : c3;
    }

    float accx = 0.f, accy = 0.f, accz = 0.f;
    u64 thr = 0;
    float4 cw;
    {
        // round 0: every lane has >=4 real candidates -> no refill possible
        const u64 w = wave_min64(c0);
        cw = sP[(int)(u32)w];              // issue read; consumed next round
        if (c0 == w) { thr = c0; c0 = c1; c1 = c2; c2 = c3; c3 = UMAX; }
    }
    #pragma unroll 1
    for (int r = 1; r < KNN; r++) {
        if (c0 == UMAX) {   // rare refill: 4 smallest keys > thr
            #pragma unroll
            for (int i = 0; i < KPL; i++) {
                const u64 v = (k[i] > thr) ? k[i] : UMAX; c0 = (v < c0) ? v : c0;
            }
            #pragma unroll
            for (int i = 0; i < KPL; i++) {
                const u64 v = (k[i] > c0) ? k[i] : UMAX; c1 = (v < c1) ? v : c1;
            }
            #pragma unroll
            for (int i = 0; i < KPL; i++) {
                const u64 v = (k[i] > c1) ? k[i] : UMAX; c2 = (v < c2) ? v : c2;
            }
            #pragma unroll
            for (int i = 0; i < KPL; i++) {
                const u64 v = (k[i] > c2) ? k[i] : UMAX; c3 = (v < c3) ? v : c3;
            }
        }
        const u64 w = wave_min64(c0);       // global min; ties impossible
        const float4 cn = sP[(int)(u32)w];  // issue this round's read...
        // ...and accumulate LAST round's winner under its latency (exact order)
        accx = __fadd_rn(accx, __fsub_rn(cw.x, ax));
        accy = __fadd_rn(accy, __fsub_rn(cw.y, ay));
        accz = __fadd_rn(accz, __fsub_rn(cw.z, az));
        cw = cn;
        if (c0 == w) {                      // exactly one lane pops
            thr = c0; c0 = c1; c1 = c2; c2 = c3; c3 = UMAX;
        }
    }
    accx = __fadd_rn(accx, __fsub_rn(cw.x, ax));
    accy = __fadd_rn(accy, __fsub_rn(cw.y, ay));
    accz = __fadd_rn(accz, __fsub_rn(cw.z, az));

    if (lane == 0) {
        float* o = out + (size_t)g * 12;
        o[0] = __fmul_rn(accx, 0.0625f);   // /16 exact as *2^-4
        o[1] = __fmul_rn(accy, 0.0625f);
        o[2] = __fmul_rn(accz, 0.0625f);
        const size_t base = (size_t)obj * NPTS * 3 + (size_t)a * 3;
        o[3] = vel[base + 0];
        o[4] = vel[base + 1];
        o[5] = vel[base + 2];
        o[6] = __fsub_rn(pos[base + 0], refp[base + 0]);
        o[7] = __fsub_rn(pos[base + 1], refp[base + 1]);
        o[8] = __fsub_rn(pos[base + 2], refp[base + 2]);
        const float* ph = phys + (size_t)obj * 3;
        o[9]  = ph[0];
        o[10] = ph[1];
        o[11] = ph[2];
    }
}

extern "C" void kernel_launch(void* const* d_in, const int* in_sizes, int n_in,
                              void* d_out, int out_size, void* d_ws, size_t ws_size,
                              hipStream_t stream) {
    const float* pos  = (const float*)d_in[0];  // (4,8,2048,3)
    const float* vel  = (const float*)d_in[1];  // (4,8,2048,3)
    const float* phys = (const float*)d_in[2];  // (4,8,3)
    const float* refp = (const float*)d_in[3];  // (4,8,2048,3)
    float* out = (float*)d_out;                 // (4,8,64,12)

    const int n_obj = in_sizes[2] / 3;          // 32 objects

    // ONE dispatch, no workspace, no memset: every block recomputes the
    // (deterministic) fps prefix it needs. 16 blocks per object.
    fused_kernel<<<n_obj * 16, TPB, 0, stream>>>(pos, vel, phys, refp,
                                                 out, n_obj);
}

// Round 8
// 105.524 us; speedup vs baseline: 1.1087x; 1.1087x over previous
//
#include <hip/hip_runtime.h>
#include <stdint.h>

// Problem constants (fixed by setup_inputs: B=4, N_obj=8, N_v=2048)
#define NPTS 2048
#define KNN  16
#define AK   64
#define TPB  256
#define FPT  (NPTS / TPB)   // 8 points per thread
#define KPL  (NPTS / 64)    // 32 points per lane (one wave per anchor)

typedef unsigned long long u64;
typedef unsigned int u32;
typedef unsigned short u16;
#define UMAX 0xFFFFFFFFFFFFFFFFull

// Exact float32 helpers (no FMA contraction -> match reference bitwise)
__device__ __forceinline__ float sq3(float x, float y, float z) {
    return __fadd_rn(__fadd_rn(__fmul_rn(x, x), __fmul_rn(y, y)), __fmul_rn(z, z));
}

// Raw workgroup barrier WITHOUT the vmcnt(0) drain __syncthreads imposes.
// LDS is the only cross-wave medium in the fps loop, so lgkmcnt(0) is the
// only ordering needed; outstanding global publish stores stay in flight.
// "memory"-clobber asm on both sides fences compiler reordering of the
// surrounding ds_write/ds_read. (Pattern proven by the guide's 8-phase
// GEMM template: raw s_barrier + counted waitcnt.)
#define BAR_LDS() do {                                        \
    asm volatile("s_waitcnt lgkmcnt(0)" ::: "memory");        \
    __builtin_amdgcn_s_barrier();                             \
    asm volatile("" ::: "memory");                            \
} while (0)

// ---------------------------------------------------------------------------
// 64-lane butterfly reductions on u64 keys, ALL-VALU.
// Stages 1,2,4,8: DPP permutations (xor1/xor2/xor4/xor8 once groups uniform).
// Stages 16,32: gfx950 v_permlane16_swap / v_permlane32_swap with self;
// reducing with BOTH results realizes the xor exchange (self-compares are
// no-ops). Harness-verified (absmax 0.0) in rounds 1-7.
// ---------------------------------------------------------------------------
template <int CTRL>
__device__ __forceinline__ u64 dpp64(u64 k) {
    const int lo = __builtin_amdgcn_update_dpp((int)(u32)k, (int)(u32)k,
                                               CTRL, 0xF, 0xF, false);
    const int hi = __builtin_amdgcn_update_dpp((int)(u32)(k >> 32),
                                               (int)(u32)(k >> 32),
                                               CTRL, 0xF, 0xF, false);
    return ((u64)(u32)hi << 32) | (u32)lo;
}

__device__ __forceinline__ void swap16_pair(u64 k, u64& a, u64& b) {
#if __has_builtin(__builtin_amdgcn_permlane16_swap)
    const u32 lo = (u32)k, hi = (u32)(k >> 32);
    const auto rl = __builtin_amdgcn_permlane16_swap(lo, lo, false, false);
    const auto rh = __builtin_amdgcn_permlane16_swap(hi, hi, false, false);
    a = ((u64)(u32)rh[0] << 32) | (u32)rl[0];
    b = ((u64)(u32)rh[1] << 32) | (u32)rl[1];
#else
    a = (u64)__shfl_xor((long long)k, 16, 64);
    b = a;
#endif
}

__device__ __forceinline__ void swap32_pair(u64 k, u64& a, u64& b) {
#if __has_builtin(__builtin_amdgcn_permlane32_swap)
    const u32 lo = (u32)k, hi = (u32)(k >> 32);
    const auto rl = __builtin_amdgcn_permlane32_swap(lo, lo, false, false);
    const auto rh = __builtin_amdgcn_permlane32_swap(hi, hi, false, false);
    a = ((u64)(u32)rh[0] << 32) | (u32)rl[0];
    b = ((u64)(u32)rh[1] << 32) | (u32)rl[1];
#else
    a = (u64)__shfl_xor((long long)k, 32, 64);
    b = a;
#endif
}

__device__ __forceinline__ u64 wave_max64(u64 k) {
    u64 o, a, b;
    o = dpp64<0xB1>(k);  if (o > k) k = o;
    o = dpp64<0x4E>(k);  if (o > k) k = o;
    o = dpp64<0x141>(k); if (o > k) k = o;
    o = dpp64<0x140>(k); if (o > k) k = o;
    swap16_pair(k, a, b); if (a > k) k = a; if (b > k) k = b;
    swap32_pair(k, a, b); if (a > k) k = a; if (b > k) k = b;
    return k;
}

__device__ __forceinline__ u64 wave_min64(u64 k) {
    u64 o, a, b;
    o = dpp64<0xB1>(k);  if (o < k) k = o;
    o = dpp64<0x4E>(k);  if (o < k) k = o;
    o = dpp64<0x141>(k); if (o < k) k = o;
    o = dpp64<0x140>(k); if (o < k) k = o;
    swap16_pair(k, a, b); if (a < k) k = a; if (b < k) k = b;
    swap32_pair(k, a, b); if (a < k) k = a; if (b < k) k = b;
    return k;
}

// ---------------------------------------------------------------------------
// KNN/gather body for one wave, one anchor. Byte-exact semantics of the
// harness-verified rounds 2-7 body (keys unique -> pop order == lax.top_k
// order; ascending-distance accumulation; exact-rounded fp ops throughout).
// ---------------------------------------------------------------------------
__device__ __forceinline__ void knn_body(
    const float4* __restrict__ sP, int a, int g, int obj, int lane,
    const float* __restrict__ pos, const float* __restrict__ vel,
    const float* __restrict__ phys, const float* __restrict__ refp,
    float* __restrict__ out) {
    const float4 ca = sP[a];
    const float ax = ca.x, ay = ca.y, az = ca.z;
    const float sqa = ca.w;     // identical bits to reference's sq[a]

    // d2 row exactly as reference: (sq_a + sq_j) - 2*dot, sign-flip sortable.
    u64 k[KPL];
    #pragma unroll
    for (int i = 0; i < KPL; i++) {
        const int j = lane + i * 64;
        const float4 p = sP[j];
        const float dot = __fadd_rn(
            __fadd_rn(__fmul_rn(ax, p.x), __fmul_rn(ay, p.y)), __fmul_rn(az, p.z));
        const float d2 = __fsub_rn(__fadd_rn(sqa, p.w), __fmul_rn(2.0f, dot));
        u32 bb = __float_as_uint(d2);
        bb ^= (bb & 0x80000000u) ? 0xFFFFFFFFu : 0x80000000u;
        k[i] = (j == a) ? UMAX : (((u64)bb << 32) | (u32)j);
    }

    // per-lane 4 smallest, ascending: c0 < c1 < c2 < c3 (keys unique)
    u64 c0 = UMAX, c1 = UMAX, c2 = UMAX, c3 = UMAX;
    #pragma unroll
    for (int i = 0; i < KPL; i++) c0 = (k[i] < c0) ? k[i] : c0;
    #pragma unroll
    for (int i = 0; i < KPL; i++) {
        const u64 v = (k[i] > c0) ? k[i] : UMAX; c1 = (v < c1) ? v : c1;
    }
    #pragma unroll
    for (int i = 0; i < KPL; i++) {
        const u64 v = (k[i] > c1) ? k[i] : UMAX; c2 = (v < c2) ? v : c2;
    }
    #pragma unroll
    for (int i = 0; i < KPL; i++) {
        const u64 v = (k[i] > c2) ? k[i] : UMAX; c3 = (v < c3) ? v : c3;
    }

    float accx = 0.f, accy = 0.f, accz = 0.f;
    u64 thr = 0;
    float4 cw;
    {
        // round 0: every lane has >=4 real candidates -> no refill possible
        const u64 w = wave_min64(c0);
        cw = sP[(int)(u32)w];              // issue read; consumed next round
        if (c0 == w) { thr = c0; c0 = c1; c1 = c2; c2 = c3; c3 = UMAX; }
    }
    #pragma unroll 1
    for (int r = 1; r < KNN; r++) {
        if (c0 == UMAX) {   // rare refill: 4 smallest keys > thr
            #pragma unroll
            for (int i = 0; i < KPL; i++) {
                const u64 v = (k[i] > thr) ? k[i] : UMAX; c0 = (v < c0) ? v : c0;
            }
            #pragma unroll
            for (int i = 0; i < KPL; i++) {
                const u64 v = (k[i] > c0) ? k[i] : UMAX; c1 = (v < c1) ? v : c1;
            }
            #pragma unroll
            for (int i = 0; i < KPL; i++) {
                const u64 v = (k[i] > c1) ? k[i] : UMAX; c2 = (v < c2) ? v : c2;
            }
            #pragma unroll
            for (int i = 0; i < KPL; i++) {
                const u64 v = (k[i] > c2) ? k[i] : UMAX; c3 = (v < c3) ? v : c3;
            }
        }
        const u64 w = wave_min64(c0);       // global min; ties impossible
        const float4 cn = sP[(int)(u32)w];  // issue this round's read...
        // ...and accumulate LAST round's winner under its latency (exact order)
        accx = __fadd_rn(accx, __fsub_rn(cw.x, ax));
        accy = __fadd_rn(accy, __fsub_rn(cw.y, ay));
        accz = __fadd_rn(accz, __fsub_rn(cw.z, az));
        cw = cn;
        if (c0 == w) {                      // exactly one lane pops
            thr = c0; c0 = c1; c1 = c2; c2 = c3; c3 = UMAX;
        }
    }
    accx = __fadd_rn(accx, __fsub_rn(cw.x, ax));
    accy = __fadd_rn(accy, __fsub_rn(cw.y, ay));
    accz = __fadd_rn(accz, __fsub_rn(cw.z, az));

    if (lane == 0) {
        float* o = out + (size_t)g * 12;
        o[0] = __fmul_rn(accx, 0.0625f);   // /16 exact as *2^-4
        o[1] = __fmul_rn(accy, 0.0625f);
        o[2] = __fmul_rn(accz, 0.0625f);
        const size_t base = (size_t)obj * NPTS * 3 + (size_t)a * 3;
        o[3] = vel[base + 0];
        o[4] = vel[base + 1];
        o[5] = vel[base + 2];
        o[6] = __fsub_rn(pos[base + 0], refp[base + 0]);
        o[7] = __fsub_rn(pos[base + 1], refp[base + 1]);
        o[8] = __fsub_rn(pos[base + 2], refp[base + 2]);
        const float* ph = phys + (size_t)obj * 3;
        o[9]  = ph[0];
        o[10] = ph[1];
        o[11] = ph[2];
    }
}

// ---------------------------------------------------------------------------
// FUSED kernel, v3. 512 blocks, one dispatch + one small memset.
//  blocks [0, n_obj):        FPS producer (R2's best-measured structure).
//    - fps-loop barriers are BAR_LDS(): raw s_barrier + lgkmcnt(0) only, so
//      the per-quad relaxed agent-scope publish stores (quads 0..14) are
//      fire-and-forget — no vmcnt(0) drain on the critical path (the
//      diagnosed ~2-2.5us of R6 slack).
//    - the producer stages sq in sP.w (fps ignores w) and runs the QUAD-15
//      KNN ITSELF from register-held anchors 60..63 — the kernel tail no
//      longer pays a publish->MALL->poll round trip (~1us).
//  blocks [n_obj, n_obj*16): KNN consumer for quads 0..14. Stages its LDS
//    tile immediately (overlapped under fps), then lane0 polls ITS OWN u64
//    (relaxed agent-scope, s_sleep(8)) until nonzero. Nonzero-proof: FPS
//    anchors are distinct, so at most one of any 4 packed anchors is index
//    0 -> the quad word is never 0.
// Co-residency: 33KB LDS, ~52 VGPR -> 4 blocks/CU capacity; 512 blocks on
// 256 CUs -> all resident regardless of dispatch order -> poll is
// deadlock-free. aq[] zeroed by hipMemsetAsync each iteration
// (graph-capture-legal) -> stale workspace can never release a consumer.
// ---------------------------------------------------------------------------
__global__ __launch_bounds__(TPB) void fused_kernel(
    const float* __restrict__ pos, const float* __restrict__ vel,
    const float* __restrict__ phys, const float* __restrict__ refp,
    u64* __restrict__ aq, float* __restrict__ out, int n_obj) {
    const int b = blockIdx.x;
    const int t = threadIdx.x;
    const int wid = t >> 6, lane = t & 63;

    __shared__ float4 sP[NPTS];   // (x,y,z,sq) point tile, 32 KB
    __shared__ u64 skey[8];       // fps: double-buffered per-wave winner keys
    __shared__ float4 scrd[8];    // fps: double-buffered per-wave winner coords
    __shared__ u64 sQ;            // knn: the polled quad word

    if (b < n_obj) {
        // ================= FPS producer (R2 structure, verified) ============
        const int obj = b;
        const float* pts = pos + (size_t)obj * NPTS * 3;
        float px[FPT], py[FPT], pz[FPT], mind[FPT];
        #pragma unroll
        for (int i = 0; i < FPT; i++) {
            const int j = t + i * TPB;
            const float x = pts[j * 3 + 0];
            const float y = pts[j * 3 + 1];
            const float z = pts[j * 3 + 2];
            px[i] = x; py[i] = y; pz[i] = z;
            sP[j] = make_float4(x, y, z, sq3(x, y, z));  // sq for own knn tail
        }
        __syncthreads();

        // quad accumulator: 4 most recent anchor ids, earliest in low 16 bits
        u64 qacc = 0;
        #define PUSH_AID(v) qacc = (qacc >> 16) | ((u64)(u16)(v) << 48)
        PUSH_AID(0);   // anchor 0 is point 0
        u32 pa0 = 0, pa1 = 0, pa2 = 0, pa3 = 0;   // producer's own quad 15

        u64 key;
        {
            const float4 c0 = sP[0];   // broadcast read
            float bv = -1.0f; u32 bj = 0;
            #pragma unroll
            for (int i = 0; i < FPT; i++) {
                const float d2 = sq3(__fsub_rn(px[i], c0.x), __fsub_rn(py[i], c0.y),
                                     __fsub_rn(pz[i], c0.z));
                mind[i] = d2;
                if (d2 > bv) { bv = d2; bj = (u32)(t + i * TPB); }  // smallest j on ties
            }
            // mind >= 0 -> float bits order-monotonic; ~j -> smaller j wins ties
            key = ((u64)__float_as_uint(bv) << 32) | (u32)(~bj);
        }

        #pragma unroll 1
        for (int s = 1; s < AK; s++) {
            const u64 wk = wave_max64(key);     // all lanes hold wave-winner
            const int side = (s & 1) * 4;
            if (lane == 0) {
                const int widx = (int)(~(u32)wk);
                skey[side + wid] = wk;
                scrd[side + wid] = sP[widx];    // 1x broadcast ds_read_b128
            }
            BAR_LDS();   // raw barrier: NO vmcnt drain -> publishes in flight
            u64 ka = skey[side + 0];
            float4 ca = scrd[side + 0];
            { const u64 k1 = skey[side + 1]; const float4 qv = scrd[side + 1];
              if (k1 > ka) { ka = k1; ca = qv; } }
            { const u64 k2 = skey[side + 2]; const float4 qv = scrd[side + 2];
              if (k2 > ka) { ka = k2; ca = qv; } }
            { const u64 k3 = skey[side + 3]; const float4 qv = scrd[side + 3];
              if (k3 > ka) { ka = k3; ca = qv; } }

            const u32 aid = ~(u32)ka;
            PUSH_AID(aid);
            if ((s & 3) == 3 && s < 60 && t == 0) {   // publish quads 0..14
                __hip_atomic_store(&aq[obj * 15 + (s >> 2)], qacc,
                                   __ATOMIC_RELAXED, __HIP_MEMORY_SCOPE_AGENT);
            }
            if (s >= 60) {                  // record own quad-15 anchors
                const int r = s - 60;
                if (r == 0) pa0 = aid;
                else if (r == 1) pa1 = aid;
                else if (r == 2) pa2 = aid;
                else pa3 = aid;
            }
            if (s == AK - 1) break;

            // fused min-update + argmax scan (exact (p-b)^2 like lax.scan)
            float bv = -1.0f; u32 bj = 0;
            #pragma unroll
            for (int i = 0; i < FPT; i++) {
                const float d2 = sq3(__fsub_rn(px[i], ca.x), __fsub_rn(py[i], ca.y),
                                     __fsub_rn(pz[i], ca.z));
                const float nm = fminf(mind[i], d2);
                mind[i] = nm;
                if (nm > bv) { bv = nm; bj = (u32)(t + i * TPB); }
            }
            key = ((u64)__float_as_uint(bv) << 32) | (u32)(~bj);
        }

        // ---- producer's own knn: quad 15, anchors 60..63, no comms --------
        u32 av = pa0;
        if (wid == 1) av = pa1;
        else if (wid == 2) av = pa2;
        else if (wid == 3) av = pa3;
        knn_body(sP, (int)av, obj * AK + 60 + wid, obj, lane,
                 pos, vel, phys, refp, out);
        return;
    }

    // ================= KNN consumer (quads 0..14) ===========================
    const int g4 = b - n_obj;           // 0..479
    const int obj = g4 / 15;
    const int q = g4 % 15;
    const int g = obj * AK + q * 4 + wid;   // global anchor id

    const float* pts = pos + (size_t)obj * NPTS * 3;
    #pragma unroll
    for (int i = 0; i < FPT; i++) {
        const int j = t + i * TPB;
        const float x = pts[j * 3 + 0];
        const float y = pts[j * 3 + 1];
        const float z = pts[j * 3 + 2];
        sP[j] = make_float4(x, y, z, sq3(x, y, z));
    }
    if (t == 0) {
        u64 v;
        for (;;) {
            v = __hip_atomic_load(&aq[obj * 15 + q], __ATOMIC_RELAXED,
                                  __HIP_MEMORY_SCOPE_AGENT);
            if (v != 0) break;
            __builtin_amdgcn_s_sleep(8);
        }
        sQ = v;
    }
    __syncthreads();            // staging + anchor delivery barrier
    const int a = (int)((sQ >> (16 * wid)) & 0xFFFF);

    knn_body(sP, a, g, obj, lane, pos, vel, phys, refp, out);
}

extern "C" void kernel_launch(void* const* d_in, const int* in_sizes, int n_in,
                              void* d_out, int out_size, void* d_ws, size_t ws_size,
                              hipStream_t stream) {
    const float* pos  = (const float*)d_in[0];  // (4,8,2048,3)
    const float* vel  = (const float*)d_in[1];  // (4,8,2048,3)
    const float* phys = (const float*)d_in[2];  // (4,8,3)
    const float* refp = (const float*)d_in[3];  // (4,8,2048,3)
    float* out = (float*)d_out;                 // (4,8,64,12)

    const int n_obj = in_sizes[2] / 3;          // 32 objects
    u64* aq = (u64*)d_ws;                       // 32*15 u64 quad slots

    // zero the quad slots each iteration (graph-capture-legal async op);
    // guarantees no stale-workspace release of consumers.
    hipMemsetAsync(aq, 0, (size_t)n_obj * 15 * sizeof(u64), stream);

    fused_kernel<<<n_obj * 16, TPB, 0, stream>>>(pos, vel, phys, refp,
                                                 aq, out, n_obj);
}